// Round 1
// baseline (296.534 us; speedup 1.0000x reference)
//
#include <hip/hip_runtime.h>
#include <stdint.h>

#define BATCH 8
#define NCH 256
#define BCH 128
#define KFR 32000
#define TOUT 256008
#define KT 64
#define NTILES 500   // KFR / KT

typedef __attribute__((ext_vector_type(8))) short bf16x8;
typedef __attribute__((ext_vector_type(4))) float f32x4;

__device__ __forceinline__ unsigned short f32_to_bf16(float f) {
    unsigned int u = __builtin_bit_cast(unsigned int, f);
    u += 0x7FFFu + ((u >> 16) & 1u);   // round-to-nearest-even
    return (unsigned short)(u >> 16);
}

// Pre-pass: convert W_mask [256][128] and W_basis [16][256] fp32 -> bf16 in d_ws
__global__ void convert_weights(const float* __restrict__ Wm,
                                const float* __restrict__ Wb,
                                unsigned short* __restrict__ wbf) {
    int i = blockIdx.x * 256 + threadIdx.x;
    if (i < NCH * BCH) wbf[i] = f32_to_bf16(Wm[i]);
    if (i < 16 * NCH)  wbf[NCH * BCH + i] = f32_to_bf16(Wb[i]);
}

// LDS layout (bytes):
//  [0, 34816)           : est32 [128][68] fp32  (aliased later by xt [64][264] bf16 = 33792 B)
//  [34816, 52224)       : estT  [64][136] bf16
//  [52224, 54304)       : locout[520] fp32
#define EST32_STRIDE 68
#define ESTT_STRIDE 136
#define XT_STRIDE 264
#define BUF0_BYTES 34816
#define ESTT_BYTES 17408
#define SMEM_BYTES (BUF0_BYTES + ESTT_BYTES + 2080)

__launch_bounds__(256, 2)
__global__ void fused_decoder(const float* __restrict__ mix,
                              const float* __restrict__ est,
                              const unsigned short* __restrict__ wbf,
                              float* __restrict__ out) {
    __shared__ __align__(16) char smem[SMEM_BYTES];
    float* est32 = reinterpret_cast<float*>(smem);
    unsigned short* xt = reinterpret_cast<unsigned short*>(smem);
    unsigned short* estT = reinterpret_cast<unsigned short*>(smem + BUF0_BYTES);
    float* locout = reinterpret_cast<float*>(smem + BUF0_BYTES + ESTT_BYTES);

    const int tid = threadIdx.x;
    const int lane = tid & 63;
    const int wv = tid >> 6;        // wave 0..3, owns n-range [64*wv, 64*wv+64)
    const int l15 = lane & 15;
    const int lq = lane >> 4;

    const int bid = blockIdx.x;
    const int g = bid / NTILES;
    const int k0 = (bid % NTILES) * KT;

    // ---- preload W_mask fragments (bf16, L2-resident) into registers ----
    bf16x8 wfrag[4][4];   // [nt][ks]: A-frag of W[n][b], n=64*wv+16*nt+l15, b=32*ks+8*lq..+7
#pragma unroll
    for (int nt = 0; nt < 4; ++nt)
#pragma unroll
        for (int ks = 0; ks < 4; ++ks) {
            int n = 64 * wv + 16 * nt + l15;
            int b = 32 * ks + 8 * lq;
            wfrag[nt][ks] = *reinterpret_cast<const bf16x8*>(wbf + n * BCH + b);
        }

    // ---- phase 1: stage est tile fp32 -> LDS [b][f] (coalesced 256B/row) ----
    {
        const int frow = tid >> 4;            // 0..15
        const int fcol = (tid & 15) * 4;      // frame offset, float4
        const float* src = est + ((size_t)g * BCH) * KFR + k0 + fcol;
#pragma unroll
        for (int it = 0; it < 8; ++it) {
            int b = it * 16 + frow;
            float4 v = *reinterpret_cast<const float4*>(src + (size_t)b * KFR);
            *reinterpret_cast<float4*>(est32 + b * EST32_STRIDE + fcol) = v;
        }
    }
    __syncthreads();

    // ---- phase 2: transpose in LDS -> estT[f][b] bf16 (contiguous b for B-frags) ----
    {
        const int f = tid & 63;
        const int w4 = tid >> 6;
#pragma unroll
        for (int i = 0; i < 4; ++i) {
            int bg = w4 + 4 * i;              // 0..15 -> b = 8*bg
            bf16x8 p;
#pragma unroll
            for (int r = 0; r < 8; ++r)
                p[r] = (short)f32_to_bf16(est32[(8 * bg + r) * EST32_STRIDE + f]);
            *reinterpret_cast<bf16x8*>(estT + f * ESTT_STRIDE + 8 * bg) = p;
        }
    }
    __syncthreads();

    // ---- phase 3: GEMM1  m[n][f] = W[n][b] * est[b][f] ----
    f32x4 acc[4][4];      // [nt][ft]
#pragma unroll
    for (int nt = 0; nt < 4; ++nt)
#pragma unroll
        for (int ft = 0; ft < 4; ++ft) {
            f32x4 z = {0.f, 0.f, 0.f, 0.f};
            acc[nt][ft] = z;
        }
#pragma unroll
    for (int ft = 0; ft < 4; ++ft) {
        int f = 16 * ft + l15;
        bf16x8 bfrag[4];
#pragma unroll
        for (int ks = 0; ks < 4; ++ks)
            bfrag[ks] = *reinterpret_cast<const bf16x8*>(estT + f * ESTT_STRIDE + 32 * ks + 8 * lq);
#pragma unroll
        for (int nt = 0; nt < 4; ++nt)
#pragma unroll
            for (int ks = 0; ks < 4; ++ks)
                acc[nt][ft] = __builtin_amdgcn_mfma_f32_16x16x32_bf16(
                    wfrag[nt][ks], bfrag[ks], acc[nt][ft], 0, 0, 0);
    }

    // ---- phase 4: x = mix * relu(m), write xt[f][n] bf16 (aliases est32, dead) ----
    {
        const float* mixg = mix + ((size_t)g * NCH) * KFR + k0;
#pragma unroll
        for (int nt = 0; nt < 4; ++nt) {
            int n0 = 64 * wv + 16 * nt + 4 * lq;   // D-layout row = 4*lq + r
#pragma unroll
            for (int ft = 0; ft < 4; ++ft) {
                int f = 16 * ft + l15;             // D-layout col
                float xv[4];
#pragma unroll
                for (int r = 0; r < 4; ++r) {
                    float m = acc[nt][ft][r];
                    xv[r] = (m > 0.f) ? mixg[(size_t)(n0 + r) * KFR + f] * m : 0.f;
                }
                unsigned int lo = (unsigned int)f32_to_bf16(xv[0]) |
                                  ((unsigned int)f32_to_bf16(xv[1]) << 16);
                unsigned int hi = (unsigned int)f32_to_bf16(xv[2]) |
                                  ((unsigned int)f32_to_bf16(xv[3]) << 16);
                uint2 u; u.x = lo; u.y = hi;
                *reinterpret_cast<uint2*>(xt + f * XT_STRIDE + n0) = u;
            }
        }
    }
    __syncthreads();

    // ---- phase 5: GEMM2  y[l][f] = Wb[l][n] * x[n][f] ; wave wv handles frames 16*wv.. ----
    f32x4 acc2 = {0.f, 0.f, 0.f, 0.f};
    {
        int f = 16 * wv + l15;
#pragma unroll
        for (int ks = 0; ks < 8; ++ks) {
            bf16x8 a = *reinterpret_cast<const bf16x8*>(wbf + NCH * BCH + l15 * NCH + 32 * ks + 8 * lq);
            bf16x8 b = *reinterpret_cast<const bf16x8*>(xt + f * XT_STRIDE + 32 * ks + 8 * lq);
            acc2 = __builtin_amdgcn_mfma_f32_16x16x32_bf16(a, b, acc2, 0, 0, 0);
        }
    }

    // ---- phase 6: overlap-add into locout[520]; two race-free passes ----
    {
        int f = 16 * wv + l15;      // frame within tile
        int lb = 4 * lq;            // lout base: 0,4,8,12
        if (lq < 2) {               // louts 0..7: t = 8f+lout covers [0,512) exactly once
#pragma unroll
            for (int r = 0; r < 4; ++r) locout[8 * f + lb + r] = acc2[r];
        }
        if (tid < 8) locout[512 + tid] = 0.f;
        __syncthreads();
        if (lq >= 2) {              // louts 8..15: t covers [8,520) exactly once
#pragma unroll
            for (int r = 0; r < 4; ++r) locout[8 * f + lb + r] += acc2[r];
        }
        __syncthreads();
    }

    // ---- phase 7: global write; interior plain float4, 16 boundary floats atomic ----
    {
        float* og = out + (size_t)g * TOUT + 8 * (size_t)k0;
        if (tid >= 2 && tid < 128) {
            *reinterpret_cast<float4*>(og + 4 * tid) =
                *reinterpret_cast<const float4*>(locout + 4 * tid);
        } else if (tid < 2 || (tid >= 128 && tid < 130)) {
#pragma unroll
            for (int r = 0; r < 4; ++r)
                atomicAdd(og + 4 * tid + r, locout[4 * tid + r]);
        }
    }
}

extern "C" void kernel_launch(void* const* d_in, const int* in_sizes, int n_in,
                              void* d_out, int out_size, void* d_ws, size_t ws_size,
                              hipStream_t stream) {
    const float* mix = (const float*)d_in[0];   // [8][256][32000]
    const float* est = (const float*)d_in[1];   // [8][128][32000]
    const float* Wm  = (const float*)d_in[2];   // [256][128]
    const float* Wb  = (const float*)d_in[3];   // [16][256]
    unsigned short* wbf = (unsigned short*)d_ws;

    // zero output (atomics add onto this; replayed every graph launch -> deterministic)
    hipMemsetAsync(d_out, 0, (size_t)out_size * sizeof(float), stream);
    convert_weights<<<128, 256, 0, stream>>>(Wm, Wb, wbf);
    fused_decoder<<<BATCH * NTILES, 256, 0, stream>>>(mix, est, wbf, (float*)d_out);
}

// Round 2
// 148.739 us; speedup vs baseline: 1.9937x; 1.9937x over previous
//
#include <hip/hip_runtime.h>
#include <stdint.h>

#define BATCH 8
#define NCH 256
#define BCH 128
#define KFR 32000
#define TOUT 256008
#define KT 32
#define NTILES (KFR / KT)   // 1000

typedef __attribute__((ext_vector_type(8))) short bf16x8;
typedef __attribute__((ext_vector_type(4))) float f32x4;

__device__ __forceinline__ unsigned short f32_to_bf16(float f) {
    unsigned int u = __builtin_bit_cast(unsigned int, f);
    u += 0x7FFFu + ((u >> 16) & 1u);   // round-to-nearest-even
    return (unsigned short)(u >> 16);
}
__device__ __forceinline__ float bf16_to_f32(unsigned short h) {
    unsigned int u = ((unsigned int)h) << 16;
    return __builtin_bit_cast(float, u);
}

// Pre-pass: convert W_mask [256][128] and W_basis [16][256] fp32 -> bf16 in d_ws
__global__ void convert_weights(const float* __restrict__ Wm,
                                const float* __restrict__ Wb,
                                unsigned short* __restrict__ wbf) {
    int i = blockIdx.x * 256 + threadIdx.x;
    if (i < NCH * BCH) wbf[i] = f32_to_bf16(Wm[i]);
    if (i < 16 * NCH)  wbf[NCH * BCH + i] = f32_to_bf16(Wb[i]);
}

// LDS layout:
//   estT [32 f][136] bf16  (272 B rows, 16B-aligned)  = 8704 B
//   xt   [32 f][264] bf16  (528 B rows, 16B-aligned)  = 16896 B
//   locout[264] f32                                   = 1056 B
#define ESTT_STRIDE 136
#define XT_STRIDE 264
#define ESTT_BYTES (KT * ESTT_STRIDE * 2)
#define XT_BYTES (KT * XT_STRIDE * 2)
#define SMEM_BYTES (ESTT_BYTES + XT_BYTES + (8 * KT + 8) * 4)

__launch_bounds__(256, 4)
__global__ void fused_decoder(const float* __restrict__ mix,
                              const float* __restrict__ est,
                              const unsigned short* __restrict__ wbf,
                              float* __restrict__ out) {
    __shared__ __align__(16) char smem[SMEM_BYTES];
    unsigned short* estT = reinterpret_cast<unsigned short*>(smem);
    unsigned short* xt   = reinterpret_cast<unsigned short*>(smem + ESTT_BYTES);
    float* locout        = reinterpret_cast<float*>(smem + ESTT_BYTES + XT_BYTES);

    const int tid = threadIdx.x;
    const int lane = tid & 63;
    const int wv = tid >> 6;        // wave 0..3, owns n-range [64*wv, 64*wv+64)
    const int l15 = lane & 15;
    const int lq = lane >> 4;

    const int bid = blockIdx.x;
    const int g = bid / NTILES;
    const int k0 = (bid % NTILES) * KT;

    // ---- phase 1: stage est -> estT[f][b] bf16, transposed on the fly ----
    // unit u = (bp, f4): 2 coalesced float4 loads (rows 2bp, 2bp+1), 4 packed b32 LDS writes
    {
        const float* eg = est + ((size_t)g * BCH) * KFR + k0;
        unsigned int* dst = reinterpret_cast<unsigned int*>(estT);
#pragma unroll
        for (int it = 0; it < 2; ++it) {
            int u = it * 256 + tid;
            int f4 = u & 7;          // f block (4 frames)
            int bp = u >> 3;         // b pair, 0..63
            float4 v0 = *reinterpret_cast<const float4*>(eg + (size_t)(2 * bp) * KFR + 4 * f4);
            float4 v1 = *reinterpret_cast<const float4*>(eg + (size_t)(2 * bp + 1) * KFR + 4 * f4);
#pragma unroll
            for (int i = 0; i < 4; ++i) {
                unsigned int p = (unsigned int)f32_to_bf16((&v0.x)[i]) |
                                 ((unsigned int)f32_to_bf16((&v1.x)[i]) << 16);
                dst[(4 * f4 + i) * (ESTT_STRIDE / 2) + bp] = p;
            }
        }
    }
    __syncthreads();

    // ---- phase 2: GEMM1  m[n][f] = W[n][b] * est[b][f]; store m (bf16) to xt[f][n] ----
    f32x4 acc[4][2];
#pragma unroll
    for (int nt = 0; nt < 4; ++nt)
#pragma unroll
        for (int ft = 0; ft < 2; ++ft) {
            f32x4 z = {0.f, 0.f, 0.f, 0.f};
            acc[nt][ft] = z;
        }
#pragma unroll
    for (int nt = 0; nt < 4; ++nt) {
        int n = 64 * wv + 16 * nt + l15;
        bf16x8 wf[4];
#pragma unroll
        for (int ks = 0; ks < 4; ++ks)
            wf[ks] = *reinterpret_cast<const bf16x8*>(wbf + n * BCH + 32 * ks + 8 * lq);
#pragma unroll
        for (int ft = 0; ft < 2; ++ft) {
            int f = 16 * ft + l15;
#pragma unroll
            for (int ks = 0; ks < 4; ++ks) {
                bf16x8 bf_ = *reinterpret_cast<const bf16x8*>(estT + f * ESTT_STRIDE + 32 * ks + 8 * lq);
                acc[nt][ft] = __builtin_amdgcn_mfma_f32_16x16x32_bf16(wf[ks], bf_, acc[nt][ft], 0, 0, 0);
            }
        }
    }
    // store raw m (relu applied later; sign preserved by bf16 rounding)
#pragma unroll
    for (int nt = 0; nt < 4; ++nt) {
        int n0 = 64 * wv + 16 * nt + 4 * lq;    // D rows
#pragma unroll
        for (int ft = 0; ft < 2; ++ft) {
            int f = 16 * ft + l15;              // D cols
            uint2 u;
            u.x = (unsigned int)f32_to_bf16(acc[nt][ft][0]) |
                  ((unsigned int)f32_to_bf16(acc[nt][ft][1]) << 16);
            u.y = (unsigned int)f32_to_bf16(acc[nt][ft][2]) |
                  ((unsigned int)f32_to_bf16(acc[nt][ft][3]) << 16);
            *reinterpret_cast<uint2*>(xt + f * XT_STRIDE + n0) = u;
        }
    }
    __syncthreads();

    // ---- phase 3: x = mix * relu(m), coalesced mix float4, xt updated in place ----
    {
        const float* mg = mix + ((size_t)g * NCH) * KFR + k0;
        unsigned int* xtd = reinterpret_cast<unsigned int*>(xt);
#pragma unroll
        for (int it = 0; it < 4; ++it) {
            int u = it * 256 + tid;
            int f4 = u & 7;          // frame block
            int np = u >> 3;         // n pair, 0..127
            float4 v0 = *reinterpret_cast<const float4*>(mg + (size_t)(2 * np) * KFR + 4 * f4);
            float4 v1 = *reinterpret_cast<const float4*>(mg + (size_t)(2 * np + 1) * KFR + 4 * f4);
#pragma unroll
            for (int i = 0; i < 4; ++i) {
                int idx = (4 * f4 + i) * (XT_STRIDE / 2) + np;
                unsigned int p = xtd[idx];
                float m0 = bf16_to_f32((unsigned short)(p & 0xFFFFu));
                float m1 = bf16_to_f32((unsigned short)(p >> 16));
                float x0 = (m0 > 0.f) ? (&v0.x)[i] * m0 : 0.f;
                float x1 = (m1 > 0.f) ? (&v1.x)[i] * m1 : 0.f;
                xtd[idx] = (unsigned int)f32_to_bf16(x0) |
                           ((unsigned int)f32_to_bf16(x1) << 16);
            }
        }
    }
    __syncthreads();

    // ---- phase 4: GEMM2  y[l][f] = Wb[l][n] * x[n][f]; waves 0,1 take f-tiles ----
    f32x4 acc2 = {0.f, 0.f, 0.f, 0.f};
    if (wv < 2) {
        int f = 16 * wv + l15;
#pragma unroll
        for (int ks = 0; ks < 8; ++ks) {
            bf16x8 a = *reinterpret_cast<const bf16x8*>(wbf + NCH * BCH + l15 * NCH + 32 * ks + 8 * lq);
            bf16x8 b = *reinterpret_cast<const bf16x8*>(xt + f * XT_STRIDE + 32 * ks + 8 * lq);
            acc2 = __builtin_amdgcn_mfma_f32_16x16x32_bf16(a, b, acc2, 0, 0, 0);
        }
    }

    // ---- phase 5: overlap-add into locout[264]; two race-free passes ----
    {
        int f = 16 * wv + l15;
        int lb = 4 * lq;
        if (wv < 2 && lq < 2) {      // louts 0..7: t = 8f+l covers [0,256) once
#pragma unroll
            for (int r = 0; r < 4; ++r) locout[8 * f + lb + r] = acc2[r];
        }
        if (tid < 8) locout[256 + tid] = 0.f;
        __syncthreads();
        if (wv < 2 && lq >= 2) {     // louts 8..15: t covers [8,264) once
#pragma unroll
            for (int r = 0; r < 4; ++r) locout[8 * f + lb + r] += acc2[r];
        }
        __syncthreads();
    }

    // ---- phase 6: global write; interior plain float4, 16 boundary floats atomic ----
    {
        float* og = out + (size_t)g * TOUT + 8 * (size_t)k0;
        if (tid >= 2 && tid < 64) {
            *reinterpret_cast<float4*>(og + 4 * tid) =
                *reinterpret_cast<const float4*>(locout + 4 * tid);
        } else if (tid < 2) {
#pragma unroll
            for (int r = 0; r < 4; ++r)
                atomicAdd(og + 4 * tid + r, locout[4 * tid + r]);
        } else if (tid >= 64 && tid < 66) {
            int t = 256 + 4 * (tid - 64);
#pragma unroll
            for (int r = 0; r < 4; ++r)
                atomicAdd(og + t + r, locout[t + r]);
        }
    }
}

extern "C" void kernel_launch(void* const* d_in, const int* in_sizes, int n_in,
                              void* d_out, int out_size, void* d_ws, size_t ws_size,
                              hipStream_t stream) {
    const float* mix = (const float*)d_in[0];   // [8][256][32000]
    const float* est = (const float*)d_in[1];   // [8][128][32000]
    const float* Wm  = (const float*)d_in[2];   // [256][128]
    const float* Wb  = (const float*)d_in[3];   // [16][256]
    unsigned short* wbf = (unsigned short*)d_ws;

    hipMemsetAsync(d_out, 0, (size_t)out_size * sizeof(float), stream);
    convert_weights<<<128, 256, 0, stream>>>(Wm, Wb, wbf);
    fused_decoder<<<BATCH * NTILES, 256, 0, stream>>>(mix, est, wbf, (float*)d_out);
}